// Round 8
// baseline (7089.722 us; speedup 1.0000x reference)
//
#include <hip/hip_runtime.h>
#include <stdint.h>

#define T_STEPS 1024
#define TC 128          // chunk length; 8 chunks
#define NCHUNK (T_STEPS/TC)
#define ROLL (TC+1)     // rolling h-history slots; slot (cs-1)%129 untouched per chunk
#define D_EMB 256
#define HID 256
#define G4H 1024
#define VOCAB 32000
#define NACT 128
#define XDIM 768
#define NGRP 8

typedef __attribute__((ext_vector_type(8))) short short8;
typedef __attribute__((ext_vector_type(4))) float f32x4;
typedef __attribute__((ext_vector_type(4))) unsigned int u32x4;
typedef unsigned short u16;
typedef unsigned int u32;

__device__ __forceinline__ float bf2f(u16 u){
  union { u32 u; float f; } v; v.u = ((u32)u) << 16; return v.f;
}
__device__ __forceinline__ u16 f2bf(float f){
  union { float f; u32 u; } v; v.f = f;
  u32 u = v.u;
  return (u16)((u + 0x7FFFu + ((u >> 16) & 1u)) >> 16);
}
__device__ __forceinline__ float sigmoidf_(float x){ return 1.f/(1.f+__expf(-x)); }
__device__ __forceinline__ float tanhf_(float x){ float e = __expf(2.f*x); return 1.f - 2.f/(e+1.f); }
__device__ __forceinline__ ushort4 pack4(float4 v){
  ushort4 r; r.x=f2bf(v.x); r.y=f2bf(v.y); r.z=f2bf(v.z); r.w=f2bf(v.w); return r;
}
// Device-coherent (MALL-level) accesses: bypass L1+L2 via sc0 sc1 — the
// R3/R5-proven cross-XCD coherence path. Ordering via per-lane vmcnt drains
// + __syncthreads. (sc0-only / XCD-L2 coherence hung in R6/R7 — do not use.)
__device__ __forceinline__ void store_x4_dc(void* p, u32x4 v){
  asm volatile("global_store_dwordx4 %0, %1, off sc0 sc1" :: "v"(p), "v"(v) : "memory");
}
__device__ __forceinline__ void store_u32_dc(void* p, u32 v){
  asm volatile("global_store_dword %0, %1, off sc0 sc1" :: "v"(p), "v"(v) : "memory");
}
__device__ __forceinline__ u32x4 load_x4_dc(const void* p){
  u32x4 d;
  asm volatile("global_load_dwordx4 %0, %1, off sc0 sc1" : "=v"(d) : "v"(p) : "memory");
  return d;
}
__device__ __forceinline__ void wait_vm0(){
  asm volatile("s_waitcnt vmcnt(0)" ::: "memory");
}

// ---------------------------------------------------------------------------
// K0: transpose weights to [N][K] bf16 so MFMA B-fragments are contiguous 16B.
// ---------------------------------------------------------------------------
__global__ void k_convert(const float* Wsx, const float* Wsh, const float* Whx, const float* Whh,
                          const float* W1, const float* W2,
                          u16* Wsxt, u16* Wsht, u16* Whxt, u16* Whht, u16* W1t, u16* W2t)
{
  const long NW = 1024L*256;
  const long NW1 = 256L*768;
  const long NW2 = 128L*256;
  const long total = 4*NW + NW1 + NW2;
  for (long i = blockIdx.x*(long)blockDim.x+threadIdx.x; i<total; i += (long)gridDim.x*blockDim.x){
    long j = i;
    if (j < NW){ long n=j>>8, k=j&255; Wsxt[j] = f2bf(Wsx[k*1024+n]); continue; } j -= NW;
    if (j < NW){ long n=j>>8, k=j&255; Wsht[j] = f2bf(Wsh[k*1024+n]); continue; } j -= NW;
    if (j < NW){ long n=j>>8, k=j&255; Whxt[j] = f2bf(Whx[k*1024+n]); continue; } j -= NW;
    if (j < NW){ long n=j>>8, k=j&255; Whht[j] = f2bf(Whh[k*1024+n]); continue; } j -= NW;
    if (j < NW1){ long n=j/768, k=j%768; W1t[j] = f2bf(W1[k*256+n]); continue; } j -= NW1;
    { long n=j>>8, k=j&255; W2t[j] = f2bf(W2[k*128+n]); }
  }
}

// ---------------------------------------------------------------------------
// K1: gx chunk: gx = emb[ids[:,t]] @ Wx + bias, stored [tc][g][gate*32+u][b].
// ---------------------------------------------------------------------------
__global__ __launch_bounds__(256) void k_gx(const int* stack_ids, const int* action_ids,
    const float* wemb, const float* aemb, const u16* Wsxt, const u16* Whxt,
    const float* bs_, const float* bh_, u16* gxc_s, u16* gxc_h, int chunk_start)
{
  __shared__ __attribute__((aligned(16))) u16 Ab[64*264];
  __shared__ int sids[64];
  const int tc = blockIdx.x, lstm = blockIdx.y;
  const int t = chunk_start + tc;
  const int* ids = lstm ? action_ids : stack_ids;
  const float* emb = lstm ? aemb : wemb;
  const u16* Wxt = lstm ? Whxt : Wsxt;
  const float* bias = lstm ? bh_ : bs_;
  u16* gxc = (lstm ? gxc_h : gxc_s) + (size_t)tc*65536;
  const int tid = threadIdx.x;
  const int wave = tid>>6, lane = tid&63, quad = lane>>4, l16 = lane&15;

  if (tid < 64) sids[tid] = ids[tid*T_STEPS + t];
  __syncthreads();
  #pragma unroll
  for (int i=0;i<16;i++){
    int v = i*256 + tid; int b = v>>6, f0 = (v&63)*4;
    float4 ld = *(const float4*)(emb + (size_t)sids[b]*256 + f0);
    *(ushort4*)&Ab[b*264 + f0] = pack4(ld);
  }
  __syncthreads();

  for (int nc=0; nc<8; nc++){
    f32x4 acc[4][2];
    #pragma unroll
    for (int r=0;r<4;r++){ acc[r][0]=(f32x4)(0.f); acc[r][1]=(f32x4)(0.f); }
    #pragma unroll
    for (int kk=0;kk<8;kk++){
      short8 a[4], bfr[2];
      #pragma unroll
      for (int r=0;r<4;r++) a[r] = *(const short8*)&Ab[(r*16+l16)*264 + kk*32 + quad*8];
      #pragma unroll
      for (int c=0;c<2;c++){
        int n = nc*128 + wave*32 + c*16 + l16;
        bfr[c] = *(const short8*)(Wxt + (size_t)n*256 + kk*32 + quad*8);
      }
      #pragma unroll
      for (int r=0;r<4;r++)
        #pragma unroll
        for (int c=0;c<2;c++)
          acc[r][c] = __builtin_amdgcn_mfma_f32_16x16x32_bf16(a[r], bfr[c], acc[r][c], 0,0,0);
    }
    #pragma unroll
    for (int c=0;c<2;c++){
      int col = nc*128 + wave*32 + c*16 + l16;
      int gate = col>>8, unit = col&255;
      int g = unit>>5, lc = (gate<<5) | (unit&31);
      float bv = bias[col];
      #pragma unroll
      for (int r=0;r<4;r++){
        int b0 = r*16 + quad*4;
        ushort4 o;
        o.x = f2bf(acc[r][c][0]+bv); o.y = f2bf(acc[r][c][1]+bv);
        o.z = f2bf(acc[r][c][2]+bv); o.w = f2bf(acc[r][c][3]+bv);
        *(ushort4*)&gxc[((size_t)g*128 + lc)*64 + b0] = o;
      }
    }
  }
}

// ---------------------------------------------------------------------------
// K2: recurrence chunk. 16 blocks = 2 LSTMs x 8 groups (R5-proven structure).
// Exchange via MALL (sc0 sc1). Hybrid consume: attempt 0 loads flags+data in
// one fused batch (1 round-trip when arriving late); on miss, poll FLAGS ONLY
// (2 lines/wave) with s_sleep backoff, then fetch data once — kills the
// fused-spin fabric congestion of R5.
// ---------------------------------------------------------------------------
__global__ __launch_bounds__(128,1) void k_rec(const u16* Wsht, const u16* Whht,
    const u16* gxc_s, const u16* gxc_h, u16* roll_s, u16* roll_h,
    float* cst, u32* flags_all, int chunk_start)
{
  __shared__ __attribute__((aligned(16))) u16 Ab[64*264];   // h_{t-1}, [b][k]
  __shared__ __attribute__((aligned(16))) u16 gxb[128*88];  // gx slice [lc][b]
  __shared__ __attribute__((aligned(16))) u16 hpack[64*40]; // own h [b][u], pad 40

  const int bx = blockIdx.x;
  const int lstm = bx>>3, grp = bx&7;
  const u16* Wht = lstm ? Whht : Wsht;
  const u16* gxc = lstm ? gxc_h : gxc_s;
  u16* roll      = lstm ? roll_h : roll_s;
  u32* flags = flags_all + lstm*(T_STEPS*8);
  float* cstp = cst + (size_t)(lstm*8+grp)*32*64;
  const int tid = threadIdx.x;
  const int wave = tid>>6, lane = tid&63, quad = lane>>4, l16 = lane&15;
  const int u = wave*16 + l16;      // local unit 0..31
  const int J0 = grp*32;

  // Stationary Wh B-fragments: Bf[gate][kk], row n = gate*256 + J0 + u.
  short8 Bf[4][8];
  #pragma unroll
  for (int ct=0; ct<4; ct++){
    int n = ct*256 + J0 + u;
    #pragma unroll
    for (int kk=0; kk<8; kk++)
      Bf[ct][kk] = *(const short8*)(Wht + (size_t)n*256 + kk*32 + quad*8);
  }

  // c-state in registers: c[r*4+i2] for batch b = r*16+quad*4+i2, unit u.
  float c[16];
  if (chunk_start == 0){
    #pragma unroll
    for (int i=0;i<16;i++) c[i] = 0.f;
    for (int i = tid; i < 64*132; i += 128) ((u32*)Ab)[i] = 0;  // h_{-1}=0
  } else {
    #pragma unroll
    for (int r=0;r<4;r++){
      float4 cv = *(const float4*)(cstp + u*64 + r*16 + quad*4);
      c[r*4+0]=cv.x; c[r*4+1]=cv.y; c[r*4+2]=cv.z; c[r*4+3]=cv.w;
    }
    int slot = (chunk_start-1)%ROLL;   // final values from prev dispatch
    u32x4 tmp[16];
    #pragma unroll
    for (int i=0;i<16;i++){
      int v = i*128+tid;
      tmp[i] = load_x4_dc(roll + (size_t)slot*16384 + v*8);
    }
    wait_vm0();
    #pragma unroll
    for (int i=0;i<16;i++){
      int v = i*128+tid; int b = v>>5, seg = v&31;
      *(u32x4*)&Ab[b*264 + seg*8] = tmp[i];
    }
  }
  {
    u32x4 pf0[8];
    #pragma unroll
    for (int i=0;i<8;i++)
      pf0[i] = *(const u32x4*)(gxc + (size_t)grp*8192 + (i*128+tid)*8);
    #pragma unroll
    for (int i=0;i<8;i++){
      int v = i*128+tid; int lc = v>>3, b0 = (v&7)*8;
      *(u32x4*)&gxb[lc*88 + b0] = pf0[i];
    }
  }
  __syncthreads();

  for (int tc=0; tc<TC; tc++){
    const int t = chunk_start + tc;
    const bool dopf = (tc+1 < TC);
    u32x4 pf[8];
    if (dopf){
      #pragma unroll
      for (int i=0;i<8;i++)
        pf[i] = *(const u32x4*)(gxc + (size_t)(tc+1)*65536 + (size_t)grp*8192 + (i*128+tid)*8);
    }
    // GEMM: preact[b][gate*32+u] = h_{t-1} @ Wh_slice
    f32x4 acc[4][4];
    #pragma unroll
    for (int r=0;r<4;r++)
      #pragma unroll
      for (int ct=0;ct<4;ct++) acc[r][ct] = (f32x4)(0.f);
    #pragma unroll
    for (int kk=0;kk<8;kk++){
      short8 a[4];
      #pragma unroll
      for (int r=0;r<4;r++) a[r] = *(const short8*)&Ab[(r*16+l16)*264 + kk*32 + quad*8];
      #pragma unroll
      for (int r=0;r<4;r++)
        #pragma unroll
        for (int ct=0;ct<4;ct++)
          acc[r][ct] = __builtin_amdgcn_mfma_f32_16x16x32_bf16(a[r], Bf[ct][kk], acc[r][ct], 0,0,0);
    }
    // LSTM cell in registers; h -> hpack LDS tile [b][u] (stride 40).
    #pragma unroll
    for (int r=0;r<4;r++){
      int b0 = r*16 + quad*4;
      ushort4 g0 = *(const ushort4*)&gxb[(0*32+u)*88 + b0];
      ushort4 g1 = *(const ushort4*)&gxb[(1*32+u)*88 + b0];
      ushort4 g2 = *(const ushort4*)&gxb[(2*32+u)*88 + b0];
      ushort4 g3 = *(const ushort4*)&gxb[(3*32+u)*88 + b0];
      const u16* p0 = (const u16*)&g0; const u16* p1 = (const u16*)&g1;
      const u16* p2 = (const u16*)&g2; const u16* p3 = (const u16*)&g3;
      #pragma unroll
      for (int i2=0;i2<4;i2++){
        float gi = acc[r][0][i2] + bf2f(p0[i2]);
        float gf = acc[r][1][i2] + bf2f(p1[i2]);
        float gg = acc[r][2][i2] + bf2f(p2[i2]);
        float go = acc[r][3][i2] + bf2f(p3[i2]);
        float cc = sigmoidf_(gf)*c[r*4+i2] + sigmoidf_(gi)*tanhf_(gg);
        c[r*4+i2] = cc;
        float h = sigmoidf_(go)*tanhf_(cc);
        hpack[(b0+i2)*40 + u] = f2bf(h);
      }
    }
    if (tc == TC-1){
      #pragma unroll
      for (int r=0;r<4;r++){
        float4 cv; cv.x=c[r*4+0]; cv.y=c[r*4+1]; cv.z=c[r*4+2]; cv.w=c[r*4+3];
        *(float4*)(cstp + u*64 + r*16 + quad*4) = cv;
      }
    }
    __syncthreads();   // hpack complete; Ab/gxb fully consumed
    // Publish own slice: 2 coherent dwordx4 stores/lane, full 64B lines.
    const int slot_w = t % ROLL;
    u16* rslot = roll + (size_t)slot_w*16384;
    #pragma unroll
    for (int i=0;i<2;i++){
      int v = i*128+tid; int b = v>>2, u0 = (v&3)*8;
      u32x4 d = *(const u32x4*)&hpack[b*40 + u0];
      store_x4_dc(rslot + b*256 + J0 + u0, d);
    }
    if (dopf){
      // local work while stores drain: own slice -> Ab, gx prefetch -> gxb
      #pragma unroll
      for (int i=0;i<2;i++){
        int v = i*128+tid; int b = v>>2, u0 = (v&3)*8;
        *(u32x4*)&Ab[b*264 + J0 + u0] = *(const u32x4*)&hpack[b*40 + u0];
      }
      #pragma unroll
      for (int i=0;i<8;i++){
        int v = i*128+tid; int lc = v>>3, b0 = (v&7)*8;
        *(u32x4*)&gxb[lc*88 + b0] = pf[i];
      }
    }
    wait_vm0();        // every lane: own h stores at coherence point
    __syncthreads();
    if (tid == 0) store_u32_dc(&flags[t*8 + grp], 1u);
    if (dopf){
      u32x4 fl0, fl1, dat[14];
      // Attempt 0: fused flags+data batch (1 round-trip if we arrived late).
      fl0 = load_x4_dc(&flags[t*8]);
      fl1 = load_x4_dc(&flags[t*8+4]);
      #pragma unroll
      for (int i=0;i<14;i++){
        int lin = i*128 + tid; int gi = lin>>8, cc = lin&255;
        int g = gi + (gi >= grp ? 1 : 0);
        int b = cc>>2, u0 = (cc&3)*8;
        dat[i] = load_x4_dc(rslot + b*256 + g*32 + u0);
      }
      wait_vm0();
      u32 all;
      {
        u32 fa0=(grp==0)?1u:fl0.x, fa1=(grp==1)?1u:fl0.y;
        u32 fa2=(grp==2)?1u:fl0.z, fa3=(grp==3)?1u:fl0.w;
        u32 fa4=(grp==4)?1u:fl1.x, fa5=(grp==5)?1u:fl1.y;
        u32 fa6=(grp==6)?1u:fl1.z, fa7=(grp==7)?1u:fl1.w;
        all = fa0 & fa1 & fa2 & fa3 & fa4 & fa5 & fa6 & fa7;
      }
      if (all != 1u){
        // Fallback: poll FLAGS ONLY (2 lines) with backoff — no data traffic.
        while (true){
          __builtin_amdgcn_s_sleep(2);
          fl0 = load_x4_dc(&flags[t*8]);
          fl1 = load_x4_dc(&flags[t*8+4]);
          wait_vm0();
          u32 fa0=(grp==0)?1u:fl0.x, fa1=(grp==1)?1u:fl0.y;
          u32 fa2=(grp==2)?1u:fl0.z, fa3=(grp==3)?1u:fl0.w;
          u32 fa4=(grp==4)?1u:fl1.x, fa5=(grp==5)?1u:fl1.y;
          u32 fa6=(grp==6)?1u:fl1.z, fa7=(grp==7)?1u:fl1.w;
          if ((fa0 & fa1 & fa2 & fa3 & fa4 & fa5 & fa6 & fa7) == 1u) break;
        }
        // Data fetch, once.
        #pragma unroll
        for (int i=0;i<14;i++){
          int lin = i*128 + tid; int gi = lin>>8, cc = lin&255;
          int g = gi + (gi >= grp ? 1 : 0);
          int b = cc>>2, u0 = (cc&3)*8;
          dat[i] = load_x4_dc(rslot + b*256 + g*32 + u0);
        }
        wait_vm0();
      }
      #pragma unroll
      for (int i=0;i<14;i++){
        int lin = i*128 + tid; int gi = lin>>8, cc = lin&255;
        int g = gi + (gi >= grp ? 1 : 0);
        int b = cc>>2, u0 = (cc&3)*8;
        *(u32x4*)&Ab[b*264 + g*32 + u0] = dat[i];
      }
      __syncthreads();
    }
  }
}

// ---------------------------------------------------------------------------
// K3: fused MLP + log-softmax + NLL for one chunk. One block per t.
// ---------------------------------------------------------------------------
__global__ __launch_bounds__(256) void k_mlp(const int* buffer_ids, const int* action_ids,
    const float* wemb, const u16* roll_s, const u16* roll_h, const u16* W1t, const float* b1,
    const u16* W2t, const float* b2, float* out, int chunk_start)
{
  __shared__ __attribute__((aligned(16))) char arena[51456];
  u16* Axb = (u16*)arena;              // [64][136] bf16 (layer1 A chunk)
  u16* lgb = (u16*)arena;              // [64][132] bf16 logits (aliases Axb)
  u16* y1b = (u16*)(arena + 17408);    // [64][264] bf16
  int* sids = (int*)(arena + 51200);

  const int t = chunk_start + blockIdx.x;
  const int tid = threadIdx.x;
  const int wave = tid>>6, lane = tid&63, quad = lane>>4, l16 = lane&15;
  if (tid < 64) sids[tid] = buffer_ids[tid*T_STEPS + t];

  f32x4 acc1[4][4];   // [nc][r]
  #pragma unroll
  for (int nc=0;nc<4;nc++)
    #pragma unroll
    for (int r=0;r<4;r++) acc1[nc][r] = (f32x4)(0.f);

  for (int kc=0; kc<6; kc++){
    __syncthreads();
    if (kc < 2){
      #pragma unroll
      for (int i=0;i<8;i++){
        int v = i*256+tid; int b = v>>5, seg = v&31;
        float4 ld = *(const float4*)(wemb + (size_t)sids[b]*256 + kc*128 + seg*4);
        *(ushort4*)&Axb[b*136 + seg*4] = pack4(ld);
      }
    } else {
      const u16* roll = (kc < 4) ? roll_h : roll_s;
      int half = kc & 1;
      if (t == 0){
        uint4 z = make_uint4(0,0,0,0);
        #pragma unroll
        for (int i=0;i<4;i++){
          int v = i*256+tid; int b = v>>4, seg = v&15;
          *(uint4*)&Axb[b*136 + seg*8] = z;
        }
      } else {
        int slot = (t-1) % ROLL;
        #pragma unroll
        for (int i=0;i<4;i++){
          int v = i*256+tid; int b = v>>4, seg = v&15;
          *(uint4*)&Axb[b*136 + seg*8] =
            *(const uint4*)(roll + (size_t)slot*16384 + b*256 + half*128 + seg*8);
        }
      }
    }
    __syncthreads();
    #pragma unroll
    for (int nc=0;nc<4;nc++){
      int n = nc*64 + wave*16 + l16;
      #pragma unroll
      for (int kk=0;kk<4;kk++){
        short8 a[4];
        #pragma unroll
        for (int r=0;r<4;r++) a[r] = *(const short8*)&Axb[(r*16+l16)*136 + kk*32 + quad*8];
        short8 bb = *(const short8*)(W1t + (size_t)n*768 + kc*128 + kk*32 + quad*8);
        #pragma unroll
        for (int r=0;r<4;r++)
          acc1[nc][r] = __builtin_amdgcn_mfma_f32_16x16x32_bf16(a[r], bb, acc1[nc][r], 0,0,0);
      }
    }
  }
  // layer1 epilogue: relu -> y1b
  #pragma unroll
  for (int nc=0;nc<4;nc++){
    int col = nc*64 + wave*16 + l16;
    float bv = b1[col];
    #pragma unroll
    for (int r=0;r<4;r++)
      #pragma unroll
      for (int i2=0;i2<4;i2++){
        int row = r*16 + quad*4 + i2;
        float y = acc1[nc][r][i2] + bv;
        y1b[row*264 + col] = f2bf(y > 0.f ? y : 0.f);
      }
  }
  __syncthreads();
  // layer2: logits = y1 @ W2 + b2
  f32x4 acc2[4][2];
  #pragma unroll
  for (int r=0;r<4;r++){ acc2[r][0]=(f32x4)(0.f); acc2[r][1]=(f32x4)(0.f); }
  #pragma unroll
  for (int kk=0;kk<8;kk++){
    short8 a[4], bb[2];
    #pragma unroll
    for (int r=0;r<4;r++) a[r] = *(const short8*)&y1b[(r*16+l16)*264 + kk*32 + quad*8];
    #pragma unroll
    for (int c2=0;c2<2;c2++){
      int n = wave*32 + c2*16 + l16;
      bb[c2] = *(const short8*)(W2t + (size_t)n*256 + kk*32 + quad*8);
    }
    #pragma unroll
    for (int r=0;r<4;r++)
      #pragma unroll
      for (int c2=0;c2<2;c2++)
        acc2[r][c2] = __builtin_amdgcn_mfma_f32_16x16x32_bf16(a[r], bb[c2], acc2[r][c2], 0,0,0);
  }
  #pragma unroll
  for (int c2=0;c2<2;c2++){
    int col = wave*32 + c2*16 + l16;
    float bv = b2[col];
    #pragma unroll
    for (int r=0;r<4;r++)
      #pragma unroll
      for (int i2=0;i2<4;i2++)
        lgb[(r*16+quad*4+i2)*132 + col] = f2bf(acc2[r][c2][i2] + bv);
  }
  __syncthreads();
  // log-softmax + NLL: one batch row per lane of wave 0
  if (tid < 64){
    int b = tid;
    float m = -1e30f;
    for (int j=0;j<128;j++) m = fmaxf(m, bf2f(lgb[b*132+j]));
    float s = 0.f;
    for (int j=0;j<128;j++) s += __expf(bf2f(lgb[b*132+j]) - m);
    int tgt = action_ids[b*T_STEPS + t];
    float v = __logf(s) + m - bf2f(lgb[b*132 + tgt]);
    #pragma unroll
    for (int o=32;o>0;o>>=1) v += __shfl_down(v, o);
    if (tid == 0) atomicAdd(out, v);
  }
}

// ---------------------------------------------------------------------------
extern "C" void kernel_launch(void* const* d_in, const int* in_sizes, int n_in,
                              void* d_out, int out_size, void* d_ws, size_t ws_size,
                              hipStream_t stream)
{
  (void)in_sizes; (void)n_in; (void)out_size; (void)ws_size;
  const int* stack_ids  = (const int*)d_in[0];
  const int* buffer_ids = (const int*)d_in[1];
  const int* action_ids = (const int*)d_in[2];
  const float* word_emb   = (const float*)d_in[3];
  const float* action_emb = (const float*)d_in[4];
  const float* Wsx = (const float*)d_in[5];
  const float* Wsh = (const float*)d_in[6];
  const float* bs  = (const float*)d_in[7];
  const float* Whx = (const float*)d_in[8];
  const float* Whh = (const float*)d_in[9];
  const float* bh  = (const float*)d_in[10];
  const float* W1  = (const float*)d_in[11];
  const float* b1  = (const float*)d_in[12];
  const float* W2  = (const float*)d_in[13];
  const float* b2  = (const float*)d_in[14];
  float* out = (float*)d_out;

  char* ws = (char*)d_ws;
  size_t off = 0;
  auto alloc = [&](size_t bytes){ char* p = ws + off; off += (bytes + 255) & ~(size_t)255; return p; };
  u16* Wsxt = (u16*)alloc(1024*256*2);
  u16* Wsht = (u16*)alloc(1024*256*2);
  u16* Whxt = (u16*)alloc(1024*256*2);
  u16* Whht = (u16*)alloc(1024*256*2);
  u16* W1t  = (u16*)alloc(256*768*2);
  u16* W2t  = (u16*)alloc(128*256*2);
  u16* gxc_s = (u16*)alloc((size_t)TC*8*128*64*2);   // 16.8 MB
  u16* gxc_h = (u16*)alloc((size_t)TC*8*128*64*2);   // 16.8 MB
  u16* roll_s = (u16*)alloc((size_t)ROLL*64*256*2);  // 4.2 MB
  u16* roll_h = (u16*)alloc((size_t)ROLL*64*256*2);  // 4.2 MB
  float* cst  = (float*)alloc(2*8*32*64*4);
  u32* flags  = (u32*)alloc(2*T_STEPS*8*4);          // [lstm][t][g]

  (void)hipMemsetAsync(flags, 0, 2*T_STEPS*8*4, stream);
  (void)hipMemsetAsync(out, 0, sizeof(float), stream);
  k_convert<<<512, 256, 0, stream>>>(Wsx, Wsh, Whx, Whh, W1, W2,
                                     Wsxt, Wsht, Whxt, Whht, W1t, W2t);
  for (int ch=0; ch<NCHUNK; ch++){
    int cs = ch*TC;
    k_gx<<<dim3(TC,2), 256, 0, stream>>>(stack_ids, action_ids, word_emb, action_emb,
                                         Wsxt, Whxt, bs, bh, gxc_s, gxc_h, cs);
    k_rec<<<16, 128, 0, stream>>>(Wsht, Whht, gxc_s, gxc_h, roll_s, roll_h, cst, flags, cs);
    k_mlp<<<TC, 256, 0, stream>>>(buffer_ids, action_ids, word_emb, roll_s, roll_h,
                                  W1t, b1, W2t, b2, out, cs);
  }
}

// Round 9
// 5356.499 us; speedup vs baseline: 1.3236x; 1.3236x over previous
//
#include <hip/hip_runtime.h>
#include <stdint.h>

#define T_STEPS 1024
#define TC 128          // chunk length; 8 chunks
#define NCHUNK (T_STEPS/TC)
#define ROLL (TC+1)     // rolling h-history slots; slot (cs-1)%129 untouched per chunk
#define D_EMB 256
#define HID 256
#define VOCAB 32000
#define NACT 128
#define XDIM 768

typedef __attribute__((ext_vector_type(8))) short short8;
typedef __attribute__((ext_vector_type(4))) float f32x4;
typedef unsigned short u16;
typedef unsigned int u32;
typedef unsigned char u8;

__device__ __forceinline__ float bf2f(u16 u){
  union { u32 u; float f; } v; v.u = ((u32)u) << 16; return v.f;
}
__device__ __forceinline__ u16 f2bf(float f){
  union { float f; u32 u; } v; v.f = f;
  u32 u = v.u;
  return (u16)((u + 0x7FFFu + ((u >> 16) & 1u)) >> 16);
}
__device__ __forceinline__ float sigmoidf_(float x){ return 1.f/(1.f+__expf(-x)); }
__device__ __forceinline__ float tanhf_(float x){ float e = __expf(2.f*x); return 1.f - 2.f/(e+1.f); }
__device__ __forceinline__ ushort4 pack4(float4 v){
  ushort4 r; r.x=f2bf(v.x); r.y=f2bf(v.y); r.z=f2bf(v.z); r.w=f2bf(v.w); return r;
}
__device__ __forceinline__ u8 f2e4m3(float v){
  u32 p = __builtin_amdgcn_cvt_pk_fp8_f32(v, v, 0, false);
  return (u8)(p & 0xff);
}

// ---------------------------------------------------------------------------
// K0: weight prep. bf16 [N][K] transposes for k_gx/k_mlp; fp8 e4m3 [col][k]
// (scaled x32 to dodge e4m3 subnormals) for the recurrent Wh.
// ---------------------------------------------------------------------------
__global__ void k_convert(const float* Wsx, const float* Wsh, const float* Whx, const float* Whh,
                          const float* W1, const float* W2,
                          u16* Wsxt, u16* Whxt, u8* Wsh8, u8* Whh8, u16* W1t, u16* W2t)
{
  const long NW = 1024L*256;
  const long NW1 = 256L*768;
  const long NW2 = 128L*256;
  const long total = 4*NW + NW1 + NW2;
  for (long i = blockIdx.x*(long)blockDim.x+threadIdx.x; i<total; i += (long)gridDim.x*blockDim.x){
    long j = i;
    if (j < NW){ long n=j>>8, k=j&255; Wsxt[j] = f2bf(Wsx[k*1024+n]); continue; } j -= NW;
    if (j < NW){ long n=j>>8, k=j&255; Whxt[j] = f2bf(Whx[k*1024+n]); continue; } j -= NW;
    if (j < NW){ long n=j>>8, k=j&255; Wsh8[j] = f2e4m3(Wsh[k*1024+n]*32.f); continue; } j -= NW;
    if (j < NW){ long n=j>>8, k=j&255; Whh8[j] = f2e4m3(Whh[k*1024+n]*32.f); continue; } j -= NW;
    if (j < NW1){ long n=j/768, k=j%768; W1t[j] = f2bf(W1[k*256+n]); continue; } j -= NW1;
    { long n=j>>8, k=j&255; W2t[j] = f2bf(W2[k*128+n]); }
  }
}

// ---------------------------------------------------------------------------
// K1: gx chunk: gx = emb[ids[:,t]] @ Wx + bias. Output layout for the
// batch-partitioned k_rec: [tc][bq(4)][col 0..1023][row-in-quarter 0..15].
// ---------------------------------------------------------------------------
__global__ __launch_bounds__(256) void k_gx(const int* stack_ids, const int* action_ids,
    const float* wemb, const float* aemb, const u16* Wsxt, const u16* Whxt,
    const float* bs_, const float* bh_, u16* gxc_s, u16* gxc_h, int chunk_start)
{
  __shared__ __attribute__((aligned(16))) u16 Ab[64*264];
  __shared__ int sids[64];
  const int tc = blockIdx.x, lstm = blockIdx.y;
  const int t = chunk_start + tc;
  const int* ids = lstm ? action_ids : stack_ids;
  const float* emb = lstm ? aemb : wemb;
  const u16* Wxt = lstm ? Whxt : Wsxt;
  const float* bias = lstm ? bh_ : bs_;
  u16* gxc = (lstm ? gxc_h : gxc_s) + (size_t)tc*65536;
  const int tid = threadIdx.x;
  const int wave = tid>>6, lane = tid&63, quad = lane>>4, l16 = lane&15;

  if (tid < 64) sids[tid] = ids[tid*T_STEPS + t];
  __syncthreads();
  #pragma unroll
  for (int i=0;i<16;i++){
    int v = i*256 + tid; int b = v>>6, f0 = (v&63)*4;
    float4 ld = *(const float4*)(emb + (size_t)sids[b]*256 + f0);
    *(ushort4*)&Ab[b*264 + f0] = pack4(ld);
  }
  __syncthreads();

  for (int nc=0; nc<8; nc++){
    f32x4 acc[4][2];
    #pragma unroll
    for (int r=0;r<4;r++){ acc[r][0]=(f32x4)(0.f); acc[r][1]=(f32x4)(0.f); }
    #pragma unroll
    for (int kk=0;kk<8;kk++){
      short8 a[4], bfr[2];
      #pragma unroll
      for (int r=0;r<4;r++) a[r] = *(const short8*)&Ab[(r*16+l16)*264 + kk*32 + quad*8];
      #pragma unroll
      for (int c=0;c<2;c++){
        int n = nc*128 + wave*32 + c*16 + l16;
        bfr[c] = *(const short8*)(Wxt + (size_t)n*256 + kk*32 + quad*8);
      }
      #pragma unroll
      for (int r=0;r<4;r++)
        #pragma unroll
        for (int c=0;c<2;c++)
          acc[r][c] = __builtin_amdgcn_mfma_f32_16x16x32_bf16(a[r], bfr[c], acc[r][c], 0,0,0);
    }
    #pragma unroll
    for (int c=0;c<2;c++){
      int col = nc*128 + wave*32 + c*16 + l16;
      float bv = bias[col];
      #pragma unroll
      for (int r=0;r<4;r++){
        // rows b0..b0+3 with b0 = r*16+quad*4 -> batch-quarter bq = r,
        // row-in-quarter = quad*4..+3
        ushort4 o;
        o.x = f2bf(acc[r][c][0]+bv); o.y = f2bf(acc[r][c][1]+bv);
        o.z = f2bf(acc[r][c][2]+bv); o.w = f2bf(acc[r][c][3]+bv);
        *(ushort4*)&gxc[((size_t)r*1024 + col)*16 + quad*4] = o;
      }
    }
  }
}

// ---------------------------------------------------------------------------
// K2: recurrence, batch-partitioned: 8 blocks = 2 LSTMs x 4 batch-quarters
// (16 rows each). ZERO inter-block communication. Full Wh held in VGPRs as
// fp8 e4m3 MFMA B-fragments (256 KB/block = 64 longs/lane); h ping-pong as
// fp8 in LDS; c-state in registers; gx (bf16) added in fp32 before the cell.
// Scaling: Wh x32, h x16 at fp8; acc x (1/512) in epilogue.
// ---------------------------------------------------------------------------
__global__ __launch_bounds__(256,1) void k_rec(const u8* Wsh8, const u8* Whh8,
    const u16* gxc_s, const u16* gxc_h, u16* roll_s, u16* roll_h,
    float* cst, int chunk_start)
{
  __shared__ __attribute__((aligned(8))) char h8[2][16*264];  // fp8 h, [row][unit]

  const int bxx = blockIdx.x;
  const int lstm = bxx>>2, bq = bxx&3;
  const u8* Wh8 = lstm ? Whh8 : Wsh8;
  const u16* gxc = lstm ? gxc_h : gxc_s;
  u16* roll      = lstm ? roll_h : roll_s;
  const int tid = threadIdx.x;
  const int w = tid>>6, lane = tid&63, quad = lane>>4, l16 = lane&15;
  float* cstp = cst + ((((size_t)lstm*4 + bq)*4 + w)*64 + lane)*16;

  // Stationary Wh fragments: Bf[ct][kk], ct = usub*4+gate,
  // col = gate*256 + w*64 + usub*16 + l16; frag covers k = kk*32 + quad*8 ..+8
  long Bf[16][8];
  #pragma unroll
  for (int ct=0; ct<16; ct++){
    int gate = ct & 3, usub = ct >> 2;
    int col = gate*256 + w*64 + usub*16 + l16;
    #pragma unroll
    for (int kk=0; kk<8; kk++)
      Bf[ct][kk] = *(const long*)(Wh8 + (size_t)col*256 + kk*32 + quad*8);
  }

  float c[16];  // c[usub*4+i2]: row=quad*4+i2, unit=w*64+usub*16+l16
  if (chunk_start == 0){
    #pragma unroll
    for (int i=0;i<16;i++) c[i] = 0.f;
    for (int i = tid; i < 1056; i += 256) ((int*)h8[0])[i] = 0;
  } else {
    #pragma unroll
    for (int r=0;r<4;r++){
      float4 cv = *(const float4*)(cstp + r*4);
      c[r*4+0]=cv.x; c[r*4+1]=cv.y; c[r*4+2]=cv.z; c[r*4+3]=cv.w;
    }
    int slot = (chunk_start-1)%ROLL;
    #pragma unroll
    for (int i=0;i<16;i++){
      int idx = i*256 + tid; int row = idx>>8, unit = idx&255;
      float hf = bf2f(roll[(size_t)slot*16384 + (bq*16+row)*256 + unit]) * 16.f;
      h8[0][row*264 + unit] = (char)f2e4m3(hf);
    }
  }
  __syncthreads();

  int par = 0;
  for (int tc=0; tc<TC; tc++){
    const int t = chunk_start + tc;
    // gx prefetch: 4 bf16 rows (quad*4..+3) per col-tile
    uint2 gxr[16];
    #pragma unroll
    for (int ct=0; ct<16; ct++){
      int gate = ct & 3, usub = ct >> 2;
      int col = gate*256 + w*64 + usub*16 + l16;
      gxr[ct] = *(const uint2*)(gxc + (size_t)tc*65536 + ((size_t)col*16 + quad*4));
    }
    // GEMM: preact = h_{t-1} @ Wh (fp8 MFMA, fp32 acc)
    f32x4 acc[16];
    #pragma unroll
    for (int ct=0;ct<16;ct++) acc[ct] = (f32x4)(0.f);
    #pragma unroll
    for (int kk=0;kk<8;kk++){
      long a = *(const long*)&h8[par][l16*264 + kk*32 + quad*8];
      #pragma unroll
      for (int ct=0;ct<16;ct++)
        acc[ct] = __builtin_amdgcn_mfma_f32_16x16x32_fp8_fp8(a, Bf[ct][kk], acc[ct], 0,0,0);
    }
    // cell (in-lane: all 4 gates of each unit live in this lane's accs)
    const int slot_w = t % ROLL;
    #pragma unroll
    for (int usub=0; usub<4; usub++){
      const u16* gI = (const u16*)&gxr[usub*4+0];
      const u16* gF = (const u16*)&gxr[usub*4+1];
      const u16* gG = (const u16*)&gxr[usub*4+2];
      const u16* gO = (const u16*)&gxr[usub*4+3];
      #pragma unroll
      for (int i2=0;i2<4;i2++){
        float gi = acc[usub*4+0][i2]*(1.f/512.f) + bf2f(gI[i2]);
        float gf = acc[usub*4+1][i2]*(1.f/512.f) + bf2f(gF[i2]);
        float gg = acc[usub*4+2][i2]*(1.f/512.f) + bf2f(gG[i2]);
        float go = acc[usub*4+3][i2]*(1.f/512.f) + bf2f(gO[i2]);
        float cc = sigmoidf_(gf)*c[usub*4+i2] + sigmoidf_(gi)*tanhf_(gg);
        c[usub*4+i2] = cc;
        float h = sigmoidf_(go)*tanhf_(cc);
        int row = quad*4 + i2;
        int unit = w*64 + usub*16 + l16;
        roll[(size_t)slot_w*16384 + (bq*16+row)*256 + unit] = f2bf(h);
        h8[par^1][row*264 + unit] = (char)f2e4m3(h*16.f);
      }
    }
    __syncthreads();
    par ^= 1;
  }
  #pragma unroll
  for (int r=0;r<4;r++){
    float4 cv; cv.x=c[r*4+0]; cv.y=c[r*4+1]; cv.z=c[r*4+2]; cv.w=c[r*4+3];
    *(float4*)(cstp + r*4) = cv;
  }
}

// ---------------------------------------------------------------------------
// K3: fused MLP + log-softmax + NLL for one chunk. One block per t.
// ---------------------------------------------------------------------------
__global__ __launch_bounds__(256) void k_mlp(const int* buffer_ids, const int* action_ids,
    const float* wemb, const u16* roll_s, const u16* roll_h, const u16* W1t, const float* b1,
    const u16* W2t, const float* b2, float* out, int chunk_start)
{
  __shared__ __attribute__((aligned(16))) char arena[51456];
  u16* Axb = (u16*)arena;              // [64][136] bf16 (layer1 A chunk)
  u16* lgb = (u16*)arena;              // [64][132] bf16 logits (aliases Axb)
  u16* y1b = (u16*)(arena + 17408);    // [64][264] bf16
  int* sids = (int*)(arena + 51200);

  const int t = chunk_start + blockIdx.x;
  const int tid = threadIdx.x;
  const int wave = tid>>6, lane = tid&63, quad = lane>>4, l16 = lane&15;
  if (tid < 64) sids[tid] = buffer_ids[tid*T_STEPS + t];

  f32x4 acc1[4][4];   // [nc][r]
  #pragma unroll
  for (int nc=0;nc<4;nc++)
    #pragma unroll
    for (int r=0;r<4;r++) acc1[nc][r] = (f32x4)(0.f);

  for (int kc=0; kc<6; kc++){
    __syncthreads();
    if (kc < 2){
      #pragma unroll
      for (int i=0;i<8;i++){
        int v = i*256+tid; int b = v>>5, seg = v&31;
        float4 ld = *(const float4*)(wemb + (size_t)sids[b]*256 + kc*128 + seg*4);
        *(ushort4*)&Axb[b*136 + seg*4] = pack4(ld);
      }
    } else {
      const u16* roll = (kc < 4) ? roll_h : roll_s;
      int half = kc & 1;
      if (t == 0){
        uint4 z = make_uint4(0,0,0,0);
        #pragma unroll
        for (int i=0;i<4;i++){
          int v = i*256+tid; int b = v>>4, seg = v&15;
          *(uint4*)&Axb[b*136 + seg*8] = z;
        }
      } else {
        int slot = (t-1) % ROLL;
        #pragma unroll
        for (int i=0;i<4;i++){
          int v = i*256+tid; int b = v>>4, seg = v&15;
          *(uint4*)&Axb[b*136 + seg*8] =
            *(const uint4*)(roll + (size_t)slot*16384 + b*256 + half*128 + seg*8);
        }
      }
    }
    __syncthreads();
    #pragma unroll
    for (int nc=0;nc<4;nc++){
      int n = nc*64 + wave*16 + l16;
      #pragma unroll
      for (int kk=0;kk<4;kk++){
        short8 a[4];
        #pragma unroll
        for (int r=0;r<4;r++) a[r] = *(const short8*)&Axb[(r*16+l16)*136 + kk*32 + quad*8];
        short8 bb = *(const short8*)(W1t + (size_t)n*768 + kc*128 + kk*32 + quad*8);
        #pragma unroll
        for (int r=0;r<4;r++)
          acc1[nc][r] = __builtin_amdgcn_mfma_f32_16x16x32_bf16(a[r], bb, acc1[nc][r], 0,0,0);
      }
    }
  }
  // layer1 epilogue: relu -> y1b
  #pragma unroll
  for (int nc=0;nc<4;nc++){
    int col = nc*64 + wave*16 + l16;
    float bv = b1[col];
    #pragma unroll
    for (int r=0;r<4;r++)
      #pragma unroll
      for (int i2=0;i2<4;i2++){
        int row = r*16 + quad*4 + i2;
        float y = acc1[nc][r][i2] + bv;
        y1b[row*264 + col] = f2bf(y > 0.f ? y : 0.f);
      }
  }
  __syncthreads();
  // layer2: logits = y1 @ W2 + b2
  f32x4 acc2[4][2];
  #pragma unroll
  for (int r=0;r<4;r++){ acc2[r][0]=(f32x4)(0.f); acc2[r][1]=(f32x4)(0.f); }
  #pragma unroll
  for (int kk=0;kk<8;kk++){
    short8 a[4], bb[2];
    #pragma unroll
    for (int r=0;r<4;r++) a[r] = *(const short8*)&y1b[(r*16+l16)*264 + kk*32 + quad*8];
    #pragma unroll
    for (int c2=0;c2<2;c2++){
      int n = wave*32 + c2*16 + l16;
      bb[c2] = *(const short8*)(W2t + (size_t)n*256 + kk*32 + quad*8);
    }
    #pragma unroll
    for (int r=0;r<4;r++)
      #pragma unroll
      for (int c2=0;c2<2;c2++)
        acc2[r][c2] = __builtin_amdgcn_mfma_f32_16x16x32_bf16(a[r], bb[c2], acc2[r][c2], 0,0,0);
  }
  #pragma unroll
  for (int c2=0;c2<2;c2++){
    int col = wave*32 + c2*16 + l16;
    float bv = b2[col];
    #pragma unroll
    for (int r=0;r<4;r++)
      #pragma unroll
      for (int i2=0;i2<4;i2++)
        lgb[(r*16+quad*4+i2)*132 + col] = f2bf(acc2[r][c2][i2] + bv);
  }
  __syncthreads();
  // log-softmax + NLL: one batch row per lane of wave 0
  if (tid < 64){
    int b = tid;
    float m = -1e30f;
    for (int j=0;j<128;j++) m = fmaxf(m, bf2f(lgb[b*132+j]));
    float s = 0.f;
    for (int j=0;j<128;j++) s += __expf(bf2f(lgb[b*132+j]) - m);
    int tgt = action_ids[b*T_STEPS + t];
    float v = __logf(s) + m - bf2f(lgb[b*132 + tgt]);
    #pragma unroll
    for (int o=32;o>0;o>>=1) v += __shfl_down(v, o);
    if (tid == 0) atomicAdd(out, v);
  }
}

// ---------------------------------------------------------------------------
extern "C" void kernel_launch(void* const* d_in, const int* in_sizes, int n_in,
                              void* d_out, int out_size, void* d_ws, size_t ws_size,
                              hipStream_t stream)
{
  (void)in_sizes; (void)n_in; (void)out_size; (void)ws_size;
  const int* stack_ids  = (const int*)d_in[0];
  const int* buffer_ids = (const int*)d_in[1];
  const int* action_ids = (const int*)d_in[2];
  const float* word_emb   = (const float*)d_in[3];
  const float* action_emb = (const float*)d_in[4];
  const float* Wsx = (const float*)d_in[5];
  const float* Wsh = (const float*)d_in[6];
  const float* bs  = (const float*)d_in[7];
  const float* Whx = (const float*)d_in[8];
  const float* Whh = (const float*)d_in[9];
  const float* bh  = (const float*)d_in[10];
  const float* W1  = (const float*)d_in[11];
  const float* b1  = (const float*)d_in[12];
  const float* W2  = (const float*)d_in[13];
  const float* b2  = (const float*)d_in[14];
  float* out = (float*)d_out;

  char* ws = (char*)d_ws;
  size_t off = 0;
  auto alloc = [&](size_t bytes){ char* p = ws + off; off += (bytes + 255) & ~(size_t)255; return p; };
  u16* Wsxt = (u16*)alloc(1024*256*2);
  u16* Whxt = (u16*)alloc(1024*256*2);
  u8*  Wsh8 = (u8*)alloc(1024*256);
  u8*  Whh8 = (u8*)alloc(1024*256);
  u16* W1t  = (u16*)alloc(256*768*2);
  u16* W2t  = (u16*)alloc(128*256*2);
  u16* gxc_s = (u16*)alloc((size_t)TC*65536*2);      // 16.8 MB
  u16* gxc_h = (u16*)alloc((size_t)TC*65536*2);      // 16.8 MB
  u16* roll_s = (u16*)alloc((size_t)ROLL*64*256*2);  // 4.2 MB
  u16* roll_h = (u16*)alloc((size_t)ROLL*64*256*2);  // 4.2 MB
  float* cst  = (float*)alloc(2*4*4*64*16*4);

  (void)hipMemsetAsync(out, 0, sizeof(float), stream);
  k_convert<<<512, 256, 0, stream>>>(Wsx, Wsh, Whx, Whh, W1, W2,
                                     Wsxt, Whxt, Wsh8, Whh8, W1t, W2t);
  for (int ch=0; ch<NCHUNK; ch++){
    int cs = ch*TC;
    k_gx<<<dim3(TC,2), 256, 0, stream>>>(stack_ids, action_ids, word_emb, action_emb,
                                         Wsxt, Whxt, bs, bh, gxc_s, gxc_h, cs);
    k_rec<<<8, 256, 0, stream>>>(Wsh8, Whh8, gxc_s, gxc_h, roll_s, roll_h, cst, cs);
    k_mlp<<<TC, 256, 0, stream>>>(buffer_ids, action_ids, word_emb, roll_s, roll_h,
                                  W1t, b1, W2t, b2, out, cs);
  }
}

// Round 10
// 4585.838 us; speedup vs baseline: 1.5460x; 1.1681x over previous
//
#include <hip/hip_runtime.h>
#include <stdint.h>

#define T_STEPS 1024
#define TC 128          // chunk length; 8 chunks
#define NCHUNK (T_STEPS/TC)
#define ROLL (TC+1)     // rolling h-history slots; slot (cs-1)%129 untouched per chunk
#define D_EMB 256
#define HID 256
#define VOCAB 32000
#define NACT 128
#define XDIM 768

typedef __attribute__((ext_vector_type(8))) short short8;
typedef __attribute__((ext_vector_type(4))) float f32x4;
typedef unsigned short u16;
typedef unsigned int u32;
typedef unsigned char u8;

__device__ __forceinline__ float bf2f(u16 u){
  union { u32 u; float f; } v; v.u = ((u32)u) << 16; return v.f;
}
__device__ __forceinline__ u16 f2bf(float f){
  union { float f; u32 u; } v; v.f = f;
  u32 u = v.u;
  return (u16)((u + 0x7FFFu + ((u >> 16) & 1u)) >> 16);
}
__device__ __forceinline__ float sigmoidf_(float x){ return 1.f/(1.f+__expf(-x)); }
__device__ __forceinline__ float tanhf_(float x){ float e = __expf(2.f*x); return 1.f - 2.f/(e+1.f); }
__device__ __forceinline__ ushort4 pack4(float4 v){
  ushort4 r; r.x=f2bf(v.x); r.y=f2bf(v.y); r.z=f2bf(v.z); r.w=f2bf(v.w); return r;
}
__device__ __forceinline__ u8 f2e4m3(float v){
  u32 p = __builtin_amdgcn_cvt_pk_fp8_f32(v, v, 0, false);
  return (u8)(p & 0xff);
}

// ---------------------------------------------------------------------------
// K0: weight prep. bf16 [N][K] transposes for k_gx/k_mlp; fp8 e4m3 [col][k]
// (scaled x32 to dodge e4m3 subnormals) for the recurrent Wh.
// ---------------------------------------------------------------------------
__global__ void k_convert(const float* Wsx, const float* Wsh, const float* Whx, const float* Whh,
                          const float* W1, const float* W2,
                          u16* Wsxt, u16* Whxt, u8* Wsh8, u8* Whh8, u16* W1t, u16* W2t)
{
  const long NW = 1024L*256;
  const long NW1 = 256L*768;
  const long NW2 = 128L*256;
  const long total = 4*NW + NW1 + NW2;
  for (long i = blockIdx.x*(long)blockDim.x+threadIdx.x; i<total; i += (long)gridDim.x*blockDim.x){
    long j = i;
    if (j < NW){ long n=j>>8, k=j&255; Wsxt[j] = f2bf(Wsx[k*1024+n]); continue; } j -= NW;
    if (j < NW){ long n=j>>8, k=j&255; Whxt[j] = f2bf(Whx[k*1024+n]); continue; } j -= NW;
    if (j < NW){ long n=j>>8, k=j&255; Wsh8[j] = f2e4m3(Wsh[k*1024+n]*32.f); continue; } j -= NW;
    if (j < NW){ long n=j>>8, k=j&255; Whh8[j] = f2e4m3(Whh[k*1024+n]*32.f); continue; } j -= NW;
    if (j < NW1){ long n=j/768, k=j%768; W1t[j] = f2bf(W1[k*256+n]); continue; } j -= NW1;
    { long n=j>>8, k=j&255; W2t[j] = f2bf(W2[k*128+n]); }
  }
}

// ---------------------------------------------------------------------------
// K1: gx chunk: gx = emb[ids[:,t]] @ Wx + bias. Output layout for the
// batch-partitioned k_rec: [tc][bq(4)][col 0..1023][row-in-quarter 0..15].
// ---------------------------------------------------------------------------
__global__ __launch_bounds__(256) void k_gx(const int* stack_ids, const int* action_ids,
    const float* wemb, const float* aemb, const u16* Wsxt, const u16* Whxt,
    const float* bs_, const float* bh_, u16* gxc_s, u16* gxc_h, int chunk_start)
{
  __shared__ __attribute__((aligned(16))) u16 Ab[64*264];
  __shared__ int sids[64];
  const int tc = blockIdx.x, lstm = blockIdx.y;
  const int t = chunk_start + tc;
  const int* ids = lstm ? action_ids : stack_ids;
  const float* emb = lstm ? aemb : wemb;
  const u16* Wxt = lstm ? Whxt : Wsxt;
  const float* bias = lstm ? bh_ : bs_;
  u16* gxc = (lstm ? gxc_h : gxc_s) + (size_t)tc*65536;
  const int tid = threadIdx.x;
  const int wave = tid>>6, lane = tid&63, quad = lane>>4, l16 = lane&15;

  if (tid < 64) sids[tid] = ids[tid*T_STEPS + t];
  __syncthreads();
  #pragma unroll
  for (int i=0;i<16;i++){
    int v = i*256 + tid; int b = v>>6, f0 = (v&63)*4;
    float4 ld = *(const float4*)(emb + (size_t)sids[b]*256 + f0);
    *(ushort4*)&Ab[b*264 + f0] = pack4(ld);
  }
  __syncthreads();

  for (int nc=0; nc<8; nc++){
    f32x4 acc[4][2];
    #pragma unroll
    for (int r=0;r<4;r++){ acc[r][0]=(f32x4)(0.f); acc[r][1]=(f32x4)(0.f); }
    #pragma unroll
    for (int kk=0;kk<8;kk++){
      short8 a[4], bfr[2];
      #pragma unroll
      for (int r=0;r<4;r++) a[r] = *(const short8*)&Ab[(r*16+l16)*264 + kk*32 + quad*8];
      #pragma unroll
      for (int c=0;c<2;c++){
        int n = nc*128 + wave*32 + c*16 + l16;
        bfr[c] = *(const short8*)(Wxt + (size_t)n*256 + kk*32 + quad*8);
      }
      #pragma unroll
      for (int r=0;r<4;r++)
        #pragma unroll
        for (int c=0;c<2;c++)
          acc[r][c] = __builtin_amdgcn_mfma_f32_16x16x32_bf16(a[r], bfr[c], acc[r][c], 0,0,0);
    }
    #pragma unroll
    for (int c=0;c<2;c++){
      int col = nc*128 + wave*32 + c*16 + l16;
      float bv = bias[col];
      #pragma unroll
      for (int r=0;r<4;r++){
        ushort4 o;
        o.x = f2bf(acc[r][c][0]+bv); o.y = f2bf(acc[r][c][1]+bv);
        o.z = f2bf(acc[r][c][2]+bv); o.w = f2bf(acc[r][c][3]+bv);
        *(ushort4*)&gxc[((size_t)r*1024 + col)*16 + quad*4] = o;
      }
    }
  }
}

// ---------------------------------------------------------------------------
// K2: recurrence, batch-partitioned: 8 blocks = 2 LSTMs x 4 batch-quarters,
// 512 threads (8 waves = 2 waves/SIMD for MFMA<->VALU overlap + latency
// hiding). ZERO inter-block communication. Full Wh in registers as fp8 e4m3
// MFMA B-fragments (512 B/lane); h ping-pong fp8 in LDS; c in registers.
// Per wave: 32 units (ct = usub*4+gate, 8 tiles), 64 MFMAs + 8 cell
// updates/lane per step. Scaling: Wh x32, h x16; acc/512 in epilogue.
// ---------------------------------------------------------------------------
__global__ __launch_bounds__(512) void k_rec(const u8* Wsh8, const u8* Whh8,
    const u16* gxc_s, const u16* gxc_h, u16* roll_s, u16* roll_h,
    float* cst, int chunk_start)
{
  __shared__ __attribute__((aligned(8))) char h8[2][16*264];  // fp8 h, [row][unit]

  const int bxx = blockIdx.x;
  const int lstm = bxx>>2, bq = bxx&3;
  const u8* Wh8 = lstm ? Whh8 : Wsh8;
  const u16* gxc = lstm ? gxc_h : gxc_s;
  u16* roll      = lstm ? roll_h : roll_s;
  const int tid = threadIdx.x;
  const int w = tid>>6, lane = tid&63, quad = lane>>4, l16 = lane&15;
  float* cstp = cst + ((((size_t)lstm*4 + bq)*8 + w)*64 + lane)*8;

  // Stationary Wh fragments: Bf[ct][kk], ct = usub*4+gate,
  // col = gate*256 + w*32 + usub*16 + l16; frag covers k = kk*32 + quad*8 ..+8
  long Bf[8][8];
  #pragma unroll
  for (int ct=0; ct<8; ct++){
    int gate = ct & 3, usub = ct >> 2;
    int col = gate*256 + w*32 + usub*16 + l16;
    #pragma unroll
    for (int kk=0; kk<8; kk++)
      Bf[ct][kk] = *(const long*)(Wh8 + (size_t)col*256 + kk*32 + quad*8);
  }

  float c[8];  // c[usub*4+i2]: row=quad*4+i2, unit=w*32+usub*16+l16
  if (chunk_start == 0){
    #pragma unroll
    for (int i=0;i<8;i++) c[i] = 0.f;
    for (int i = tid; i < 1056; i += 512) ((int*)h8[0])[i] = 0;
  } else {
    #pragma unroll
    for (int r=0;r<2;r++){
      float4 cv = *(const float4*)(cstp + r*4);
      c[r*4+0]=cv.x; c[r*4+1]=cv.y; c[r*4+2]=cv.z; c[r*4+3]=cv.w;
    }
    int slot = (chunk_start-1)%ROLL;
    #pragma unroll
    for (int i=0;i<8;i++){
      int idx = i*512 + tid; int row = idx>>8, unit = idx&255;
      float hf = bf2f(roll[(size_t)slot*16384 + (bq*16+row)*256 + unit]) * 16.f;
      h8[0][row*264 + unit] = (char)f2e4m3(hf);
    }
  }
  __syncthreads();

  int par = 0;
  for (int tc=0; tc<TC; tc++){
    const int t = chunk_start + tc;
    // gx prefetch: 4 bf16 rows (quad*4..+3) per col-tile
    uint2 gxr[8];
    #pragma unroll
    for (int ct=0; ct<8; ct++){
      int gate = ct & 3, usub = ct >> 2;
      int col = gate*256 + w*32 + usub*16 + l16;
      gxr[ct] = *(const uint2*)(gxc + (size_t)tc*65536 + ((size_t)col*16 + quad*4));
    }
    // GEMM: preact = h_{t-1} @ Wh (fp8 MFMA, fp32 acc)
    f32x4 acc[8];
    #pragma unroll
    for (int ct=0;ct<8;ct++) acc[ct] = (f32x4)(0.f);
    #pragma unroll
    for (int kk=0;kk<8;kk++){
      long a = *(const long*)&h8[par][l16*264 + kk*32 + quad*8];
      #pragma unroll
      for (int ct=0;ct<8;ct++)
        acc[ct] = __builtin_amdgcn_mfma_f32_16x16x32_fp8_fp8(a, Bf[ct][kk], acc[ct], 0,0,0);
    }
    // cell (in-lane: all 4 gates of each unit live in this lane's accs)
    const int slot_w = t % ROLL;
    #pragma unroll
    for (int usub=0; usub<2; usub++){
      const u16* gI = (const u16*)&gxr[usub*4+0];
      const u16* gF = (const u16*)&gxr[usub*4+1];
      const u16* gG = (const u16*)&gxr[usub*4+2];
      const u16* gO = (const u16*)&gxr[usub*4+3];
      #pragma unroll
      for (int i2=0;i2<4;i2++){
        float gi = acc[usub*4+0][i2]*(1.f/512.f) + bf2f(gI[i2]);
        float gf = acc[usub*4+1][i2]*(1.f/512.f) + bf2f(gF[i2]);
        float gg = acc[usub*4+2][i2]*(1.f/512.f) + bf2f(gG[i2]);
        float go = acc[usub*4+3][i2]*(1.f/512.f) + bf2f(gO[i2]);
        float cc = sigmoidf_(gf)*c[usub*4+i2] + sigmoidf_(gi)*tanhf_(gg);
        c[usub*4+i2] = cc;
        float h = sigmoidf_(go)*tanhf_(cc);
        int row = quad*4 + i2;
        int unit = w*32 + usub*16 + l16;
        roll[(size_t)slot_w*16384 + (bq*16+row)*256 + unit] = f2bf(h);
        h8[par^1][row*264 + unit] = (char)f2e4m3(h*16.f);
      }
    }
    __syncthreads();
    par ^= 1;
  }
  #pragma unroll
  for (int r=0;r<2;r++){
    float4 cv; cv.x=c[r*4+0]; cv.y=c[r*4+1]; cv.z=c[r*4+2]; cv.w=c[r*4+3];
    *(float4*)(cstp + r*4) = cv;
  }
}

// ---------------------------------------------------------------------------
// K3: fused MLP + log-softmax + NLL for one chunk. One block per t.
// ---------------------------------------------------------------------------
__global__ __launch_bounds__(256) void k_mlp(const int* buffer_ids, const int* action_ids,
    const float* wemb, const u16* roll_s, const u16* roll_h, const u16* W1t, const float* b1,
    const u16* W2t, const float* b2, float* out, int chunk_start)
{
  __shared__ __attribute__((aligned(16))) char arena[51456];
  u16* Axb = (u16*)arena;              // [64][136] bf16 (layer1 A chunk)
  u16* lgb = (u16*)arena;              // [64][132] bf16 logits (aliases Axb)
  u16* y1b = (u16*)(arena + 17408);    // [64][264] bf16
  int* sids = (int*)(arena + 51200);

  const int t = chunk_start + blockIdx.x;
  const int tid = threadIdx.x;
  const int wave = tid>>6, lane = tid&63, quad = lane>>4, l16 = lane&15;
  if (tid < 64) sids[tid] = buffer_ids[tid*T_STEPS + t];

  f32x4 acc1[4][4];   // [nc][r]
  #pragma unroll
  for (int nc=0;nc<4;nc++)
    #pragma unroll
    for (int r=0;r<4;r++) acc1[nc][r] = (f32x4)(0.f);

  for (int kc=0; kc<6; kc++){
    __syncthreads();
    if (kc < 2){
      #pragma unroll
      for (int i=0;i<8;i++){
        int v = i*256+tid; int b = v>>5, seg = v&31;
        float4 ld = *(const float4*)(wemb + (size_t)sids[b]*256 + kc*128 + seg*4);
        *(ushort4*)&Axb[b*136 + seg*4] = pack4(ld);
      }
    } else {
      const u16* roll = (kc < 4) ? roll_h : roll_s;
      int half = kc & 1;
      if (t == 0){
        uint4 z = make_uint4(0,0,0,0);
        #pragma unroll
        for (int i=0;i<4;i++){
          int v = i*256+tid; int b = v>>4, seg = v&15;
          *(uint4*)&Axb[b*136 + seg*8] = z;
        }
      } else {
        int slot = (t-1) % ROLL;
        #pragma unroll
        for (int i=0;i<4;i++){
          int v = i*256+tid; int b = v>>4, seg = v&15;
          *(uint4*)&Axb[b*136 + seg*8] =
            *(const uint4*)(roll + (size_t)slot*16384 + b*256 + half*128 + seg*8);
        }
      }
    }
    __syncthreads();
    #pragma unroll
    for (int nc=0;nc<4;nc++){
      int n = nc*64 + wave*16 + l16;
      #pragma unroll
      for (int kk=0;kk<4;kk++){
        short8 a[4];
        #pragma unroll
        for (int r=0;r<4;r++) a[r] = *(const short8*)&Axb[(r*16+l16)*136 + kk*32 + quad*8];
        short8 bb = *(const short8*)(W1t + (size_t)n*768 + kc*128 + kk*32 + quad*8);
        #pragma unroll
        for (int r=0;r<4;r++)
          acc1[nc][r] = __builtin_amdgcn_mfma_f32_16x16x32_bf16(a[r], bb, acc1[nc][r], 0,0,0);
      }
    }
  }
  // layer1 epilogue: relu -> y1b
  #pragma unroll
  for (int nc=0;nc<4;nc++){
    int col = nc*64 + wave*16 + l16;
    float bv = b1[col];
    #pragma unroll
    for (int r=0;r<4;r++)
      #pragma unroll
      for (int i2=0;i2<4;i2++){
        int row = r*16 + quad*4 + i2;
        float y = acc1[nc][r][i2] + bv;
        y1b[row*264 + col] = f2bf(y > 0.f ? y : 0.f);
      }
  }
  __syncthreads();
  // layer2: logits = y1 @ W2 + b2
  f32x4 acc2[4][2];
  #pragma unroll
  for (int r=0;r<4;r++){ acc2[r][0]=(f32x4)(0.f); acc2[r][1]=(f32x4)(0.f); }
  #pragma unroll
  for (int kk=0;kk<8;kk++){
    short8 a[4], bb[2];
    #pragma unroll
    for (int r=0;r<4;r++) a[r] = *(const short8*)&y1b[(r*16+l16)*264 + kk*32 + quad*8];
    #pragma unroll
    for (int c2=0;c2<2;c2++){
      int n = wave*32 + c2*16 + l16;
      bb[c2] = *(const short8*)(W2t + (size_t)n*256 + kk*32 + quad*8);
    }
    #pragma unroll
    for (int r=0;r<4;r++)
      #pragma unroll
      for (int c2=0;c2<2;c2++)
        acc2[r][c2] = __builtin_amdgcn_mfma_f32_16x16x32_bf16(a[r], bb[c2], acc2[r][c2], 0,0,0);
  }
  #pragma unroll
  for (int c2=0;c2<2;c2++){
    int col = wave*32 + c2*16 + l16;
    float bv = b2[col];
    #pragma unroll
    for (int r=0;r<4;r++)
      #pragma unroll
      for (int i2=0;i2<4;i2++)
        lgb[(r*16+quad*4+i2)*132 + col] = f2bf(acc2[r][c2][i2] + bv);
  }
  __syncthreads();
  // log-softmax + NLL: one batch row per lane of wave 0
  if (tid < 64){
    int b = tid;
    float m = -1e30f;
    for (int j=0;j<128;j++) m = fmaxf(m, bf2f(lgb[b*132+j]));
    float s = 0.f;
    for (int j=0;j<128;j++) s += __expf(bf2f(lgb[b*132+j]) - m);
    int tgt = action_ids[b*T_STEPS + t];
    float v = __logf(s) + m - bf2f(lgb[b*132 + tgt]);
    #pragma unroll
    for (int o=32;o>0;o>>=1) v += __shfl_down(v, o);
    if (tid == 0) atomicAdd(out, v);
  }
}

// ---------------------------------------------------------------------------
extern "C" void kernel_launch(void* const* d_in, const int* in_sizes, int n_in,
                              void* d_out, int out_size, void* d_ws, size_t ws_size,
                              hipStream_t stream)
{
  (void)in_sizes; (void)n_in; (void)out_size; (void)ws_size;
  const int* stack_ids  = (const int*)d_in[0];
  const int* buffer_ids = (const int*)d_in[1];
  const int* action_ids = (const int*)d_in[2];
  const float* word_emb   = (const float*)d_in[3];
  const float* action_emb = (const float*)d_in[4];
  const float* Wsx = (const float*)d_in[5];
  const float* Wsh = (const float*)d_in[6];
  const float* bs  = (const float*)d_in[7];
  const float* Whx = (const float*)d_in[8];
  const float* Whh = (const float*)d_in[9];
  const float* bh  = (const float*)d_in[10];
  const float* W1  = (const float*)d_in[11];
  const float* b1  = (const float*)d_in[12];
  const float* W2  = (const float*)d_in[13];
  const float* b2  = (const float*)d_in[14];
  float* out = (float*)d_out;

  char* ws = (char*)d_ws;
  size_t off = 0;
  auto alloc = [&](size_t bytes){ char* p = ws + off; off += (bytes + 255) & ~(size_t)255; return p; };
  u16* Wsxt = (u16*)alloc(1024*256*2);
  u16* Whxt = (u16*)alloc(1024*256*2);
  u8*  Wsh8 = (u8*)alloc(1024*256);
  u8*  Whh8 = (u8*)alloc(1024*256);
  u16* W1t  = (u16*)alloc(256*768*2);
  u16* W2t  = (u16*)alloc(128*256*2);
  u16* gxc_s = (u16*)alloc((size_t)TC*65536*2);      // 16.8 MB
  u16* gxc_h = (u16*)alloc((size_t)TC*65536*2);      // 16.8 MB
  u16* roll_s = (u16*)alloc((size_t)ROLL*64*256*2);  // 4.2 MB
  u16* roll_h = (u16*)alloc((size_t)ROLL*64*256*2);  // 4.2 MB
  float* cst  = (float*)alloc(2*4*8*64*8*4);         // c-state, [lstm][bq][w][lane][8]

  (void)hipMemsetAsync(out, 0, sizeof(float), stream);
  k_convert<<<512, 256, 0, stream>>>(Wsx, Wsh, Whx, Whh, W1, W2,
                                     Wsxt, Whxt, Wsh8, Whh8, W1t, W2t);
  for (int ch=0; ch<NCHUNK; ch++){
    int cs = ch*TC;
    k_gx<<<dim3(TC,2), 256, 0, stream>>>(stack_ids, action_ids, word_emb, action_emb,
                                         Wsxt, Whxt, bs, bh, gxc_s, gxc_h, cs);
    k_rec<<<8, 512, 0, stream>>>(Wsh8, Whh8, gxc_s, gxc_h, roll_s, roll_h, cst, cs);
    k_mlp<<<TC, 256, 0, stream>>>(buffer_ids, action_ids, word_emb, roll_s, roll_h,
                                  W1t, b1, W2t, b2, out, cs);
  }
}